// Round 1
// baseline (279.249 us; speedup 1.0000x reference)
//
#include <hip/hip_runtime.h>
#include <math.h>

// Problem constants
#define NN 1024      // N
#define DD 64        // D
#define TT 2048      // T
#define UDEC 0.97f
#define EPS 1e-6f
// Phase-D chunking (rho/a* path)
#define CC 64        // chunk length along t
#define NCH 32       // TT/CC
#define NSL 8        // N-slices for partial Gram/inter
#define SLW 128      // slice width (NN/NSL)
// X prefix-scan chunking
#define C2 32
#define NC2 64       // TT/C2

#define NBLK 256
#define NTHR 256

// ---- dynamic-LDS overlays (max = SmP3 ~49.7 KB) ----
struct SmP1 { float Vs[C2][DD]; };
struct SmP3 { float Xs[CC][SLW + 1]; float Vw[CC][DD]; float pw[CC + 1]; };
struct SmP5 { float Xs[CC][65]; float Rs[CC][65]; };
struct SmP6 { float Ve[CC][DD]; float Gt[8][CC]; float Pt[8][DD]; float pw[CC + 1]; };
struct SmP7 { float Ys[8][NN]; float L[8][DD]; float pre[8][DD + 1]; float mrow[8]; float srow[8]; };
#define SMEM_BYTES 50176

// Monotone-counter grid barrier. Grid=256 blocks (1/CU worst-case capacity >=2/CU,
// so all blocks are always co-resident). Device-scope: release fence before arrive,
// relaxed agent-scope polls, acquire fence after.
__device__ __forceinline__ void gridbar(unsigned* cnt, unsigned target) {
    __syncthreads();
    if (threadIdx.x == 0) {
        __builtin_amdgcn_fence(__ATOMIC_RELEASE, "agent");
        atomicAdd(cnt, 1u);
        int spins = 0;
        while (__hip_atomic_load(cnt, __ATOMIC_RELAXED, __HIP_MEMORY_SCOPE_AGENT) < target) {
            __builtin_amdgcn_s_sleep(2);
            if (++spins > (1 << 22)) break;   // safety: fail loud, never hang forever
        }
        __builtin_amdgcn_fence(__ATOMIC_ACQUIRE, "agent");
    }
    __syncthreads();
}

__global__ __launch_bounds__(NTHR) void fused_bdh(
    const float* __restrict__ E, const float* __restrict__ Dx,
    const float* __restrict__ Dy, const float* __restrict__ temb,
    const float* __restrict__ x0, const float* __restrict__ rho0,
    const int* __restrict__ toks,
    float* __restrict__ ys, float* __restrict__ vs,
    float* __restrict__ Xp, float* __restrict__ S, float* __restrict__ Bb,
    float* __restrict__ M, float* __restrict__ Rho, float* __restrict__ LNA,
    float* __restrict__ Gp, float* __restrict__ Pp, unsigned* __restrict__ bar)
{
    extern __shared__ __align__(16) char smem[];
    const int b = blockIdx.x, tid = threadIdx.x;

    // ---------------- P1: X chunk-scan (r = relu(Dx v); intra-chunk prefix) ----------
    {
        SmP1* sm = (SmP1*)smem;
        const int cs = b >> 2, qx = b & 3;
        const int n = qx * 256 + tid;
        for (int i = tid; i < C2 * DD; i += NTHR) {
            int s = i >> 6, d = i & 63;
            sm->Vs[s][d] = temb[toks[cs * C2 + s] * DD + d];
        }
        __syncthreads();
        float dxr[DD];
        const float4* dx4 = reinterpret_cast<const float4*>(Dx + n * DD);
#pragma unroll
        for (int j = 0; j < 16; ++j) {
            float4 v = dx4[j];
            dxr[4*j] = v.x; dxr[4*j+1] = v.y; dxr[4*j+2] = v.z; dxr[4*j+3] = v.w;
        }
        float run = 0.f;
        for (int s = 0; s < C2; ++s) {
            const float4* vr = reinterpret_cast<const float4*>(&sm->Vs[s][0]);
            float a0 = 0.f, a1 = 0.f, a2 = 0.f, a3 = 0.f;
#pragma unroll
            for (int j = 0; j < 16; ++j) {
                float4 v = vr[j];
                a0 += v.x * dxr[4*j];     a1 += v.y * dxr[4*j+1];
                a2 += v.z * dxr[4*j+2];   a3 += v.w * dxr[4*j+3];
            }
            run += fmaxf((a0 + a1) + (a2 + a3), 0.f);
            Xp[(cs * C2 + s) * NN + n] = run;
        }
        S[cs * NN + n] = run;
    }
    gridbar(bar, 1 * NBLK);

    // ---------------- P2: exclusive scan of chunk totals -> Bb -----------------------
    if (b < 4) {
        const int n = b * 256 + tid;
        float acc = x0[n];
        for (int cs = 0; cs < NC2; ++cs) {
            Bb[cs * NN + n] = acc;
            acc += S[cs * NN + n];
        }
    }
    gridbar(bar, 2 * NBLK);

    // ---------------- P3: per (chunk, slice): M (rank collapse) + Gram ---------------
    {
        SmP3* sm = (SmP3*)smem;
        const int c = b >> 3, q = b & 7;
        if (tid <= CC) sm->pw[tid] = powf(UDEC, (float)tid);
        __syncthreads();
        for (int i = tid; i < CC * SLW; i += NTHR) {
            int s = i >> 7, n = i & 127;
            int t = c * CC + s, gn = q * SLW + n;
            sm->Xs[s][n] = Xp[t * NN + gn] + Bb[(t >> 5) * NN + gn];
        }
        for (int i = tid; i < CC * DD; i += NTHR) {
            int s = i >> 6, d = i & 63;
            sm->Vw[s][d] = temb[toks[c * CC + s] * DD + d] * sm->pw[CC - s];
        }
        __syncthreads();
        {   // M part
            const int n_l = tid & 127, dh = tid >> 7;
            float acc[32];
#pragma unroll
            for (int k = 0; k < 32; ++k) acc[k] = 0.f;
            for (int s = 0; s < CC; ++s) {
                float xv = sm->Xs[s][n_l];
                const float4* vr = reinterpret_cast<const float4*>(&sm->Vw[s][dh * 32]);
#pragma unroll
                for (int k8 = 0; k8 < 8; ++k8) {
                    float4 v = vr[k8];
                    acc[4*k8]   += v.x * xv;  acc[4*k8+1] += v.y * xv;
                    acc[4*k8+2] += v.z * xv;  acc[4*k8+3] += v.w * xv;
                }
            }
            for (int k = 0; k < 32; ++k)
                M[(c * DD + dh * 32 + k) * NN + q * SLW + n_l] = acc[k];
        }
        {   // Gram part (same staged Xs)
            const int ti = tid >> 4, sj = tid & 15;
            float acc[16];
#pragma unroll
            for (int k = 0; k < 16; ++k) acc[k] = 0.f;
            for (int n = 0; n < SLW; ++n) {
                float xt[4], xs[4];
#pragma unroll
                for (int a = 0; a < 4; ++a) xt[a] = sm->Xs[ti * 4 + a][n];
#pragma unroll
                for (int e2 = 0; e2 < 4; ++e2) xs[e2] = sm->Xs[sj * 4 + e2][n];
#pragma unroll
                for (int a = 0; a < 4; ++a)
#pragma unroll
                    for (int e2 = 0; e2 < 4; ++e2) acc[a * 4 + e2] += xt[a] * xs[e2];
            }
            float* base = Gp + ((size_t)(c * NSL + q) * CC) * CC;
#pragma unroll
            for (int a = 0; a < 4; ++a)
                *reinterpret_cast<float4*>(base + (ti * 4 + a) * CC + sj * 4) =
                    make_float4(acc[a*4], acc[a*4+1], acc[a*4+2], acc[a*4+3]);
        }
    }
    gridbar(bar, 3 * NBLK);

    // ---------------- P4: elementwise chunk scan of rho ------------------------------
    {
        const int el = b * NTHR + tid;            // covers DD*NN exactly
        float acc = rho0[el];
        const float uc = powf(UDEC, (float)CC);
        for (int c = 0; c < NCH; ++c) {
            Rho[c * (DD * NN) + el] = acc;
            acc = fmaf(acc, uc, M[c * (DD * NN) + el]);
        }
    }
    gridbar(bar, 4 * NBLK);

    // ---------------- P5: partial inter Pp[t][d] = sum_n Rho[d][n] x_t[n] ------------
    {
        SmP5* sm = (SmP5*)smem;
        const int c = b >> 3, q = b & 7;
        const int ti = tid >> 4, sj = tid & 15;
        float acc[16];
#pragma unroll
        for (int k = 0; k < 16; ++k) acc[k] = 0.f;
        for (int h = 0; h < 2; ++h) {
            __syncthreads();       // protect restage vs previous half's reads
            for (int i = tid; i < CC * 64; i += NTHR) {
                int s = i >> 6, n = i & 63;
                int t = c * CC + s, gn = q * SLW + h * 64 + n;
                sm->Xs[s][n] = Xp[t * NN + gn] + Bb[(t >> 5) * NN + gn];
                sm->Rs[s][n] = Rho[(c * DD + s) * NN + gn];
            }
            __syncthreads();
            for (int n = 0; n < 64; ++n) {
                float xt[4], rv[4];
#pragma unroll
                for (int a = 0; a < 4; ++a) xt[a] = sm->Xs[ti * 4 + a][n];
#pragma unroll
                for (int e2 = 0; e2 < 4; ++e2) rv[e2] = sm->Rs[sj * 4 + e2][n];
#pragma unroll
                for (int a = 0; a < 4; ++a)
#pragma unroll
                    for (int e2 = 0; e2 < 4; ++e2) acc[a * 4 + e2] += xt[a] * rv[e2];
            }
        }
        float* base = Pp + ((size_t)(c * NSL + q) * CC) * DD;
#pragma unroll
        for (int a = 0; a < 4; ++a)
            *reinterpret_cast<float4*>(base + (ti * 4 + a) * DD + sj * 4) =
                make_float4(acc[a*4], acc[a*4+1], acc[a*4+2], acc[a*4+3]);
    }
    gridbar(bar, 5 * NBLK);

    // ---------------- P6: a* assembly + rowwise LN (t-striped, 8 blocks/chunk) -------
    {
        SmP6* sm = (SmP6*)smem;
        const int c = b >> 3, sub = b & 7;        // block handles t = sub + 8k
        if (tid <= CC) sm->pw[tid] = powf(UDEC, (float)tid);
        for (int i = tid; i < CC * DD; i += NTHR) {
            int s = i >> 6, d = i & 63;
            sm->Ve[s][d] = temb[toks[c * CC + s] * DD + d];
        }
        for (int i = tid; i < 8 * CC; i += NTHR) {
            int k = i >> 6, s = i & 63;
            int t = sub + 8 * k;
            float ag = 0.f, ap = 0.f;
#pragma unroll
            for (int q = 0; q < NSL; ++q) {
                ag += Gp[((size_t)(c * NSL + q) * CC + t) * CC + s];
                ap += Pp[((size_t)(c * NSL + q) * CC + t) * DD + s];
            }
            sm->Gt[k][s] = ag; sm->Pt[k][s] = ap;
        }
        __syncthreads();
        const int tk = tid >> 5, d0 = tid & 31;   // 32 lanes x 2 d's per t-row
        const int t = sub + 8 * tk;
        float a0 = sm->pw[t] * sm->Pt[tk][d0];
        float a1 = sm->pw[t] * sm->Pt[tk][d0 + 32];
        for (int s = 0; s < t; ++s) {
            float w = sm->pw[t - s] * sm->Gt[tk][s];
            a0 += w * sm->Ve[s][d0];
            a1 += w * sm->Ve[s][d0 + 32];
        }
        float sum = a0 + a1;
#pragma unroll
        for (int m = 1; m < 32; m <<= 1) sum += __shfl_xor(sum, m, 32);
        float mean = sum * (1.f / DD);
        float z0 = a0 - mean, z1 = a1 - mean;
        float vsum = z0 * z0 + z1 * z1;
#pragma unroll
        for (int m = 1; m < 32; m <<= 1) vsum += __shfl_xor(vsum, m, 32);
        float inv = 1.f / (sqrtf(vsum * (1.f / (DD - 1))) + EPS);
        LNA[(c * CC + t) * DD + d0]      = z0 * inv;
        LNA[(c * CC + t) * DD + d0 + 32] = z1 * inv;
    }
    gridbar(bar, 6 * NBLK);

    // ---------------- P7: y (relu(Dy LNA)*relu(x)) then v = LN(E y), fused -----------
    {
        SmP7* sm = (SmP7*)smem;
        const int tt = b;                          // 8-token tile
        for (int i = tid; i < 8 * DD; i += NTHR) sm->L[i >> 6][i & 63] = LNA[tt * 8 * DD + i];
        __syncthreads();
        for (int nq = 0; nq < 4; ++nq) {
            const int n = nq * 256 + tid;
            float dyr[DD];
            const float4* dy4 = reinterpret_cast<const float4*>(Dy + n * DD);
#pragma unroll
            for (int j = 0; j < 16; ++j) {
                float4 v = dy4[j];
                dyr[4*j] = v.x; dyr[4*j+1] = v.y; dyr[4*j+2] = v.z; dyr[4*j+3] = v.w;
            }
#pragma unroll
            for (int t = 0; t < 8; ++t) {
                const float4* lr = reinterpret_cast<const float4*>(&sm->L[t][0]);
                float a0 = 0.f, a1 = 0.f, a2 = 0.f, a3 = 0.f;
#pragma unroll
                for (int j = 0; j < 16; ++j) {
                    float4 v = lr[j];
                    a0 += v.x * dyr[4*j];   a1 += v.y * dyr[4*j+1];
                    a2 += v.z * dyr[4*j+2]; a3 += v.w * dyr[4*j+3];
                }
                float yc = (a0 + a1) + (a2 + a3);
                int tg = tt * 8 + t;
                float xv = Xp[tg * NN + n] + Bb[(tg >> 5) * NN + n];
                float yv = fmaxf(yc, 0.f) * fmaxf(xv, 0.f);
                ys[tg * NN + n] = yv;
                sm->Ys[t][n] = yv;
            }
        }
        __syncthreads();
        const int d = tid & 63, tq = tid >> 6, t0 = tq * 2;
        const float4* e4 = reinterpret_cast<const float4*>(E + d * NN);
        float a00=0,a01=0,a02=0,a03=0, a10=0,a11=0,a12=0,a13=0;
        for (int j = 0; j < NN / 4; ++j) {
            float4 ev  = e4[j];
            float4 y0v = *reinterpret_cast<const float4*>(&sm->Ys[t0][4 * j]);
            float4 y1v = *reinterpret_cast<const float4*>(&sm->Ys[t0 + 1][4 * j]);
            a00 += ev.x * y0v.x; a01 += ev.y * y0v.y; a02 += ev.z * y0v.z; a03 += ev.w * y0v.w;
            a10 += ev.x * y1v.x; a11 += ev.y * y1v.y; a12 += ev.z * y1v.z; a13 += ev.w * y1v.w;
        }
        sm->pre[t0][d]     = (a00 + a01) + (a02 + a03);
        sm->pre[t0 + 1][d] = (a10 + a11) + (a12 + a13);
        __syncthreads();
        if (tid < 8) {
            float m = 0.f;
#pragma unroll
            for (int dd2 = 0; dd2 < DD; ++dd2) m += sm->pre[tid][dd2];
            m *= (1.f / DD);
            float v = 0.f;
#pragma unroll
            for (int dd2 = 0; dd2 < DD; ++dd2) { float z = sm->pre[tid][dd2] - m; v += z * z; }
            sm->mrow[tid] = m;
            sm->srow[tid] = 1.f / (sqrtf(v * (1.f / (DD - 1))) + EPS);
        }
        __syncthreads();
        for (int i = tid; i < 8 * DD; i += NTHR) {
            int t = i >> 6, dd2 = i & 63;
            vs[(tt * 8 + t) * DD + dd2] = (sm->pre[t][dd2] - sm->mrow[t]) * sm->srow[t];
        }
    }
}

// ---------------------------------------------------------------------------
extern "C" void kernel_launch(void* const* d_in, const int* in_sizes, int n_in,
                              void* d_out, int out_size, void* d_ws, size_t ws_size,
                              hipStream_t stream) {
    (void)in_sizes; (void)n_in; (void)out_size; (void)ws_size;
    const float* E    = (const float*)d_in[0];   // [D,N]
    const float* Dx   = (const float*)d_in[1];   // [N,D]
    const float* Dy   = (const float*)d_in[2];   // [N,D]
    const float* temb = (const float*)d_in[3];   // [V,D]
    const float* x0   = (const float*)d_in[4];   // [N]
    const float* rho0 = (const float*)d_in[5];   // [D,N]
    const int*   toks = (const int*)d_in[6];     // [T]

    float* ys = (float*)d_out;                   // [T,N]
    float* vs = ys + (size_t)TT * NN;            // [T,D]

    // Workspace (~33 MiB). No aliasing now: M and Gp are simultaneously live.
    float* w   = (float*)d_ws;
    float* Xp  = w;                               // TT*NN
    float* S   = Xp  + (size_t)TT * NN;           // NC2*NN
    float* Bb  = S   + (size_t)NC2 * NN;          // NC2*NN
    float* M   = Bb  + (size_t)NC2 * NN;          // NCH*DD*NN
    float* Rho = M   + (size_t)NCH * DD * NN;     // NCH*DD*NN
    float* LNA = Rho + (size_t)NCH * DD * NN;     // TT*DD
    float* Gp  = LNA + (size_t)TT * DD;           // NCH*NSL*CC*CC
    float* Pp  = Gp  + (size_t)NCH * NSL * CC * CC; // NCH*NSL*CC*DD
    unsigned* bar = (unsigned*)(Pp + (size_t)NCH * NSL * CC * DD);

    hipMemsetAsync(bar, 0, 64, stream);
    hipLaunchKernelGGL(fused_bdh, dim3(NBLK), dim3(NTHR), SMEM_BYTES, stream,
                       E, Dx, Dy, temb, x0, rho0, toks, ys, vs,
                       Xp, S, Bb, M, Rho, LNA, Gp, Pp, bar);
}